// Round 2
// baseline (574.760 us; speedup 1.0000x reference)
//
#include <hip/hip_runtime.h>
#include <stdint.h>

// Problem constants (fixed by setup_inputs)
#define B_ 64
#define C_ 256
#define H_ 56
#define W_ 56
#define HM 50              // H - (BLOCK_SIZE-1)
#define WM 50
#define NPLANES (B_ * C_)          // 16384
#define PLANE_IN (HM * WM)         // 2500
#define PLANE_OUT (H_ * W_)        // 3136
#define NTOT (NPLANES * PLANE_OUT) // 51,380,224

__global__ void zero_counter(unsigned int* cnt) {
    if (threadIdx.x == 0) *cnt = 0u;
}

// One block per (b,c) plane, 4 waves. Each wave builds row bitmasks via
// __ballot (lane i supplies bit i), smears horizontally (7-wide OR), then
// 56 threads do the vertical 7-row OR, invert to keep-bits, store + count.
__global__ __launch_bounds__(256) void dilate_kernel(
        const float* __restrict__ u,
        const float* __restrict__ gamma,
        unsigned long long* __restrict__ mask_out,   // [NPLANES * H_]
        unsigned int* __restrict__ counter) {
    __shared__ unsigned long long hdil[HM];    // 400 B

    const int plane = blockIdx.x;
    const int tid   = threadIdx.x;
    const int wave  = tid >> 6;
    const int lane  = tid & 63;
    const float g   = gamma[0];
    const float* up = u + (size_t)plane * PLANE_IN;

    // Rows r = wave + 4*i. Lanes 0..49 load row floats (contiguous 200 B),
    // ballot packs the predicate into a 64-bit row mask in one instruction.
    #pragma unroll
    for (int i = 0; i < 13; ++i) {
        int r = wave + 4 * i;
        float v = 1e30f;                       // predicate false for idle lanes
        if (r < HM && lane < WM) v = up[r * WM + lane];
        unsigned long long bits = __ballot(v < g);
        // horizontal dilation: OR of shifts 0..6 via log-step smear
        unsigned long long h = bits | (bits << 1);
        h |= h << 2;
        h |= h << 3;
        if (lane == 0 && r < HM) hdil[r] = h;
    }
    __syncthreads();

    // Vertical dilation: output row t covers seed rows [t-6, t] ∩ [0, HM).
    unsigned int zcnt = 0;
    if (tid < H_) {
        int r0 = tid - 6; if (r0 < 0) r0 = 0;
        int r1 = tid;     if (r1 > HM - 1) r1 = HM - 1;
        unsigned long long v = 0ull;
        for (int r = r0; r <= r1; ++r) v |= hdil[r];
        unsigned long long keep = (~v) & ((1ULL << W_) - 1ULL);
        mask_out[(size_t)plane * H_ + tid] = keep;
        zcnt = (unsigned int)__popcll(keep);
    }
    // Threads 0..55 are all in wave 0: shuffle-reduce, one atomic per block.
    if (tid < 64) {
        #pragma unroll
        for (int off = 32; off > 0; off >>= 1)
            zcnt += __shfl_down(zcnt, off, 64);
        if (tid == 0) atomicAdd(counter, zcnt);
    }
}

// One block per plane: mask row words cached in LDS, x/out as aligned float4.
__global__ __launch_bounds__(256) void apply_kernel(
        const float* __restrict__ x,
        const unsigned long long* __restrict__ mask,
        const unsigned int* __restrict__ counter,
        float* __restrict__ out) {
    __shared__ unsigned long long smask[H_];
    __shared__ float s_scale;

    const int plane = blockIdx.x;
    const int tid   = threadIdx.x;
    if (tid < H_) smask[tid] = mask[(size_t)plane * H_ + tid];
    if (tid == 0) s_scale = (float)NTOT / (float)(*counter);
    __syncthreads();
    const float scale = s_scale;

    const float4* xp = (const float4*)(x + (size_t)plane * PLANE_OUT);
    float4*       op = (float4*)(out + (size_t)plane * PLANE_OUT);

    #pragma unroll
    for (int i = 0; i < 4; ++i) {
        int idx4 = i * 256 + tid;                  // [0, 784)
        if (idx4 < PLANE_OUT / 4) {
            int h  = idx4 / 14;                    // W_/4 = 14 float4 per row
            int w4 = idx4 - h * 14;
            unsigned long long bits = smask[h] >> (w4 * 4);
            float4 v = xp[idx4];
            float4 o;
            o.x = (bits & 1ull) ? v.x * scale : 0.0f;
            o.y = (bits & 2ull) ? v.y * scale : 0.0f;
            o.z = (bits & 4ull) ? v.z * scale : 0.0f;
            o.w = (bits & 8ull) ? v.w * scale : 0.0f;
            op[idx4] = o;
        }
    }
}

extern "C" void kernel_launch(void* const* d_in, const int* in_sizes, int n_in,
                              void* d_out, int out_size, void* d_ws, size_t ws_size,
                              hipStream_t stream) {
    const float* x     = (const float*)d_in[0];
    const float* u     = (const float*)d_in[1];
    const float* gamma = (const float*)d_in[2];
    float* out = (float*)d_out;

    // Workspace: [0,4) counter; [256, 256 + NPLANES*H_*8) bit-packed keep mask.
    unsigned int* counter = (unsigned int*)d_ws;
    unsigned long long* mask = (unsigned long long*)((char*)d_ws + 256);

    zero_counter<<<1, 64, 0, stream>>>(counter);
    dilate_kernel<<<NPLANES, 256, 0, stream>>>(u, gamma, mask, counter);
    apply_kernel<<<NPLANES, 256, 0, stream>>>(x, mask, counter, out);
}

// Round 3
// 471.814 us; speedup vs baseline: 1.2182x; 1.2182x over previous
//
#include <hip/hip_runtime.h>
#include <stdint.h>

// Problem constants (fixed by setup_inputs)
#define B_ 64
#define C_ 256
#define H_ 56
#define W_ 56
#define HM 50              // H - (BLOCK_SIZE-1)
#define WM 50
#define NPLANES (B_ * C_)          // 16384
#define PLANE_IN (HM * WM)         // 2500
#define PLANE_OUT (H_ * W_)        // 3136
#define NTOT (NPLANES * PLANE_OUT) // 51,380,224
#define N4 (NTOT / 4)              // 12,845,056 float4s

// One block per (b,c) plane, 4 waves. Each wave builds row bitmasks via
// __ballot (lane i supplies bit i), smears horizontally (7-wide OR), then
// 56 threads do the vertical 7-row OR, invert to keep-bits, store + count.
// NO atomics: per-block count goes to counts[blockIdx] (contention-free).
__global__ __launch_bounds__(256) void dilate_kernel(
        const float* __restrict__ u,
        const float* __restrict__ gamma,
        unsigned long long* __restrict__ mask_out,   // [NPLANES * H_]
        unsigned int* __restrict__ counts) {         // [NPLANES]
    __shared__ unsigned long long hdil[HM];    // 400 B

    const int plane = blockIdx.x;
    const int tid   = threadIdx.x;
    const int wave  = tid >> 6;
    const int lane  = tid & 63;
    const float g   = gamma[0];
    const float* up = u + (size_t)plane * PLANE_IN;

    // Rows r = wave + 4*i. Lanes 0..49 load row floats (contiguous 200 B),
    // ballot packs the predicate into a 64-bit row mask in one instruction.
    #pragma unroll
    for (int i = 0; i < 13; ++i) {
        int r = wave + 4 * i;
        float v = 1e30f;                       // predicate false for idle lanes
        if (r < HM && lane < WM) v = up[r * WM + lane];
        unsigned long long bits = __ballot(v < g);
        // horizontal dilation: OR of shifts 0..6 via log-step smear
        unsigned long long h = bits | (bits << 1);
        h |= h << 2;
        h |= h << 3;
        if (lane == 0 && r < HM) hdil[r] = h;
    }
    __syncthreads();

    // Vertical dilation: output row t covers seed rows [t-6, t] ∩ [0, HM).
    unsigned int zcnt = 0;
    if (tid < H_) {
        int r0 = tid - 6; if (r0 < 0) r0 = 0;
        int r1 = tid;     if (r1 > HM - 1) r1 = HM - 1;
        unsigned long long v = 0ull;
        for (int r = r0; r <= r1; ++r) v |= hdil[r];
        unsigned long long keep = (~v) & ((1ULL << W_) - 1ULL);
        mask_out[(size_t)plane * H_ + tid] = keep;
        zcnt = (unsigned int)__popcll(keep);
    }
    // Threads 0..55 are all in wave 0: shuffle-reduce, store one count/block.
    if (tid < 64) {
        #pragma unroll
        for (int off = 32; off > 0; off >>= 1)
            zcnt += __shfl_down(zcnt, off, 64);
        if (tid == 0) counts[plane] = zcnt;
    }
}

// Single block: sum 16384 per-block counts, write final scale factor.
__global__ __launch_bounds__(256) void reduce_kernel(
        const unsigned int* __restrict__ counts,
        float* __restrict__ scale_out) {
    __shared__ unsigned int sdata[4];
    const int tid  = threadIdx.x;
    const int wave = tid >> 6;
    const int lane = tid & 63;

    unsigned int sum = 0;
    const uint4* c4 = (const uint4*)counts;            // 4096 uint4
    for (int i = tid; i < NPLANES / 4; i += 256) {
        uint4 v = c4[i];
        sum += v.x + v.y + v.z + v.w;
    }
    #pragma unroll
    for (int off = 32; off > 0; off >>= 1)
        sum += __shfl_down(sum, off, 64);
    if (lane == 0) sdata[wave] = sum;
    __syncthreads();
    if (tid == 0) {
        unsigned int total = sdata[0] + sdata[1] + sdata[2] + sdata[3];
        *scale_out = (float)NTOT / (float)total;
    }
}

// Grid-stride elementwise: out = x * scale * keep_bit. No LDS, no barrier —
// mask words and scale come straight from L2.
__global__ __launch_bounds__(256) void apply_kernel(
        const float* __restrict__ x,
        const unsigned long long* __restrict__ mask,
        const float* __restrict__ scale_ptr,
        float* __restrict__ out) {
    const float scale = *scale_ptr;
    const float4* xp = (const float4*)x;
    float4*       op = (float4*)out;
    const int stride = gridDim.x * 256;

    for (int idx4 = blockIdx.x * 256 + threadIdx.x; idx4 < N4; idx4 += stride) {
        int word = idx4 / 14;            // = plane*56 + h  (W_/4 == 14)
        int w4   = idx4 - word * 14;
        unsigned long long bits = mask[word] >> (w4 * 4);
        float4 v = xp[idx4];
        float4 o;
        o.x = (bits & 1ull) ? v.x * scale : 0.0f;
        o.y = (bits & 2ull) ? v.y * scale : 0.0f;
        o.z = (bits & 4ull) ? v.z * scale : 0.0f;
        o.w = (bits & 8ull) ? v.w * scale : 0.0f;
        op[idx4] = o;
    }
}

extern "C" void kernel_launch(void* const* d_in, const int* in_sizes, int n_in,
                              void* d_out, int out_size, void* d_ws, size_t ws_size,
                              hipStream_t stream) {
    const float* x     = (const float*)d_in[0];
    const float* u     = (const float*)d_in[1];
    const float* gamma = (const float*)d_in[2];
    float* out = (float*)d_out;

    // Workspace: [0,4) scale; [1024, 1024+64KB) per-block counts;
    //            [66560, +7.34MB) bit-packed keep mask.
    float*        scale  = (float*)d_ws;
    unsigned int* counts = (unsigned int*)((char*)d_ws + 1024);
    unsigned long long* mask =
        (unsigned long long*)((char*)d_ws + 1024 + NPLANES * sizeof(unsigned int));

    dilate_kernel<<<NPLANES, 256, 0, stream>>>(u, gamma, mask, counts);
    reduce_kernel<<<1, 256, 0, stream>>>(counts, scale);
    apply_kernel<<<4096, 256, 0, stream>>>(x, mask, scale, out);
}